// Round 5
// baseline (637.565 us; speedup 1.0000x reference)
//
#include <hip/hip_runtime.h>
#include <hip/hip_bf16.h>
#include <math.h>

#define NN 60000
#define NE 200000
#define DD 128
#define NH 4
#define HC 512   // NH * C
#define NL 3
#define VAv 128
#define VBv 16
#define SCAN_CHUNK 512

typedef __attribute__((ext_vector_type(8))) short bf16x8;
typedef __attribute__((ext_vector_type(4))) float f32x4;

__device__ __forceinline__ float bf2f(unsigned short u){
    union{unsigned int i; float f;} v; v.i = ((unsigned int)u)<<16; return v.f;
}
__device__ __forceinline__ unsigned short f2bf(float f){
    union{float f; unsigned int i;} v; v.f = f;
    unsigned int r = v.i + 0x7fffu + ((v.i>>16)&1u);
    return (unsigned short)(r>>16);
}

#define GLOAD_LDS16(g, l) \
    __builtin_amdgcn_global_load_lds((const __attribute__((address_space(1))) void*)(g), \
                                     (__attribute__((address_space(3))) void*)(l), 16, 0, 0)

// ---------------- embedding gather: h[n,:] = atom_emb[x[n],:] (fp32 + bf16) ----------
__global__ void k_embed(const int* __restrict__ x, const float* __restrict__ atom_emb,
                        float* __restrict__ h, unsigned short* __restrict__ hb) {
    int idx = blockIdx.x*blockDim.x + threadIdx.x;   // float4 index
    if (idx >= NN*(DD/4)) return;
    int n = idx >> 5;
    int c4 = idx & 31;
    int a = x[n];
    float4 v = ((const float4*)(atom_emb + (size_t)a*DD))[c4];
    ((float4*)(h + (size_t)n*DD))[c4] = v;
    ushort4 u = make_ushort4(f2bf(v.x), f2bf(v.y), f2bf(v.z), f2bf(v.w));
    ((ushort4*)(hb + (size_t)n*DD))[c4] = u;
}

// -------- weight convert: [Wl|Wr] -> Wlrt[l][1024][128] bf16 transposed; blr ---------
__global__ void k_convw(const float* __restrict__ Wl, const float* __restrict__ Wr,
                        const float* __restrict__ bl, const float* __restrict__ br,
                        unsigned short* __restrict__ Wlrt, float* __restrict__ blr) {
    int t = blockIdx.x*256 + threadIdx.x;
    if (t < NL*1024*DD) {
        int l = t / (1024*DD);
        int r = t % (1024*DD);
        int n = r / DD;      // 0..1023
        int k = r % DD;
        float v = (n < HC) ? Wl[(size_t)l*DD*HC + (size_t)k*HC + n]
                           : Wr[(size_t)l*DD*HC + (size_t)k*HC + (n - HC)];
        Wlrt[t] = f2bf(v);
    }
    if (t < NL*1024) {
        int l = t / 1024, j = t % 1024;
        blr[t] = (j < HC) ? bl[(size_t)l*HC + j] : br[(size_t)l*HC + (j - HC)];
    }
}

// ---------------- Wa convert: fp32 [128][128] -> bf16 transposed ---------------------
__global__ void k_convwa(const float* __restrict__ Wa, unsigned short* __restrict__ Wat) {
    int t = blockIdx.x*256 + threadIdx.x;
    if (t >= DD*VAv) return;
    int n = t / DD;
    int k = t % DD;
    Wat[t] = f2bf(Wa[(size_t)k*VAv + n]);
}

// ---------------- eproj (all layers, fp32): eprojf[l][v][n] ---------------------------
__global__ void k_eproj(const float* __restrict__ bond_emb, const float* __restrict__ We,
                        float* __restrict__ eprojf) {
    int t = blockIdx.x*256 + threadIdx.x;    // 24576 total
    if (t >= NL*VBv*HC) return;
    int n = t & (HC-1);
    int v = (t >> 9) & (VBv-1);
    int l = t >> 13;
    const float* be = bond_emb + (size_t)v*DD;         // wave-uniform -> scalar
    const float* w  = We + (size_t)l*DD*HC + n;
    float acc = 0.f;
    #pragma unroll 8
    for (int k = 0; k < DD; ++k) acc = fmaf(be[k], w[(size_t)k*HC], acc);
    eprojf[t] = acc;
}

// ---------------- CSR build ----------------
__global__ void k_deg(const int* __restrict__ dst, int* __restrict__ deg) {
    int e = blockIdx.x*blockDim.x + threadIdx.x;
    if (e < NE) atomicAdd(&deg[dst[e]], 1);
}

__global__ void k_scan1(const int* __restrict__ deg, int* __restrict__ exc, int* __restrict__ sums) {
    __shared__ int buf[2][SCAN_CHUNK];
    int t = threadIdx.x;
    int gi = blockIdx.x*SCAN_CHUNK + t;
    int v = (gi < NN) ? deg[gi] : 0;
    buf[0][t] = v;
    __syncthreads();
    int cur = 0;
    for (int off = 1; off < SCAN_CHUNK; off <<= 1) {
        int nv = buf[cur][t] + ((t >= off) ? buf[cur][t-off] : 0);
        buf[cur^1][t] = nv;
        __syncthreads();
        cur ^= 1;
    }
    if (gi < NN) exc[gi] = buf[cur][t] - v;
    if (t == SCAN_CHUNK-1) sums[blockIdx.x] = buf[cur][t];
}

__global__ void k_scan2(int* sums, int nb) {     // nb <= 128
    __shared__ int buf[2][128];
    int t = threadIdx.x;
    int v = (t < nb) ? sums[t] : 0;
    buf[0][t] = v;
    __syncthreads();
    int cur = 0;
    for (int off = 1; off < 128; off <<= 1) {
        int nv = buf[cur][t] + ((t >= off) ? buf[cur][t-off] : 0);
        buf[cur^1][t] = nv;
        __syncthreads();
        cur ^= 1;
    }
    if (t < nb) sums[t] = buf[cur][t] - v;       // exclusive
}

__global__ void k_scan3(const int* __restrict__ exc, const int* __restrict__ sums,
                        int* __restrict__ rowptr) {
    int i = blockIdx.x*blockDim.x + threadIdx.x;
    if (i < NN) rowptr[i] = exc[i] + sums[i / SCAN_CHUNK];
    if (i == NN) rowptr[NN] = NE;
}

// scatter: store src | (eattr<<16) sorted by dst  (src < 65536, eattr < 16)
__global__ void k_scatter(const int* __restrict__ srcv, const int* __restrict__ dst,
                          const int* __restrict__ eattr, const int* __restrict__ rowptr,
                          int* __restrict__ cnt, int* __restrict__ packed) {
    int e = blockIdx.x*blockDim.x + threadIdx.x;
    if (e < NE) {
        int d = dst[e];
        int pos = atomicAdd(&cnt[d], 1);
        packed[rowptr[d] + pos] = srcv[e] | (eattr[e] << 16);
    }
}

// ---------------- MFMA bf16 GEMM v2: C[M,Nc] = A[M,128] * Bt[Nc,128]^T (+bias) -------
// A staged in LDS (32 KB, ^(row&15) swizzle); B-panel fragments live in registers
// (L2-hot, loads issued under the A-staging DMA). 128x128 tile, 4 waves.
template<bool OUT_BF16>
__global__ __launch_bounds__(256)
void k_gemm_mfma(const unsigned short* __restrict__ A,
                 const unsigned short* __restrict__ Bt,
                 const float* __restrict__ bias, void* __restrict__ Cout,
                 int M, int Nc) {
    __shared__ unsigned short As[128*128/2 * 2];   // 128 rows x 128 cols bf16 = 32 KB
    int tid = threadIdx.x;
    int lane = tid & 63;
    int wave = tid >> 6;
    int bn = blockIdx.x * 128;
    int bm = blockIdx.y * 128;
    int l15 = lane & 15;
    int l4  = lane >> 4;
    int wm = (wave >> 1) * 64;
    int wn = (wave & 1) * 64;

    // A tile -> LDS, source-side swizzle so LDS slot (row, c) holds chunk c^(row&15)
    #pragma unroll
    for (int it = 0; it < 8; ++it) {
        int slot = it*256 + tid;        // 16B-chunk slot, 2048 total
        int row  = slot >> 4;
        int cph  = slot & 15;
        int clog = cph ^ (row & 15);
        int arow = bm + row; if (arow >= M) arow = M - 1;
        unsigned short* ldst = (unsigned short*)As + (size_t)(it*256 + (tid & ~63))*8;
        GLOAD_LDS16(A + (size_t)arow*128 + clog*8, ldst);
    }

    // B fragments -> registers while the DMA runs (16 rows x 64B per load, L2-hot)
    bf16x8 bfr[4][4];
    #pragma unroll
    for (int ks = 0; ks < 4; ++ks)
        #pragma unroll
        for (int ni = 0; ni < 4; ++ni)
            bfr[ks][ni] = *(const bf16x8*)(Bt + (size_t)(bn + wn + ni*16 + l15)*128
                                              + (size_t)(ks*4 + l4)*8);

    asm volatile("s_waitcnt vmcnt(0)" ::: "memory");
    __syncthreads();

    f32x4 acc[4][4];
    #pragma unroll
    for (int i = 0; i < 4; ++i)
        #pragma unroll
        for (int j = 0; j < 4; ++j)
            acc[i][j] = (f32x4){0.f, 0.f, 0.f, 0.f};

    #pragma unroll
    for (int ks = 0; ks < 4; ++ks) {
        bf16x8 af[4];
        int cph = (ks*4 + l4) ^ l15;           // row&15 == l15 for fragment rows
        #pragma unroll
        for (int mi = 0; mi < 4; ++mi) {
            int row = wm + mi*16 + l15;
            af[mi] = *(const bf16x8*)(As + (size_t)row*128 + cph*8);
        }
        #pragma unroll
        for (int mi = 0; mi < 4; ++mi)
            #pragma unroll
            for (int ni = 0; ni < 4; ++ni)
                acc[mi][ni] = __builtin_amdgcn_mfma_f32_16x16x32_bf16(af[mi], bfr[ks][ni], acc[mi][ni], 0, 0, 0);
    }

    #pragma unroll
    for (int mi = 0; mi < 4; ++mi) {
        #pragma unroll
        for (int ni = 0; ni < 4; ++ni) {
            int col = bn + wn + ni*16 + l15;
            float bv = bias ? bias[col] : 0.f;
            #pragma unroll
            for (int r = 0; r < 4; ++r) {
                int row = bm + wm + mi*16 + l4*4 + r;
                if (row < M) {
                    float v = acc[mi][ni][r] + bv;
                    if (OUT_BF16) ((unsigned short*)Cout)[(size_t)row*Nc + col] = f2bf(v);
                    else          ((float*)Cout)[(size_t)row*Nc + col] = v;
                }
            }
        }
    }
}

// ---- fused edge-logits + softmax + aggregate + epilogue ----------------------------
// 8 waves/block, one node per wave. Lane l: head h = l>>4, channels (l&15)*8..+8.
// xlr row layout: [xl 512 | xr 512] bf16.
__global__ __launch_bounds__(512)
void k_aggregate(const unsigned short* __restrict__ xlr,
                 const float* __restrict__ eprojf,   // [16][512] fp32, this layer
                 const int* __restrict__ rowptr, const int* __restrict__ packed,
                 const float* __restrict__ att,      // [4][128], this layer
                 const float* __restrict__ bias,     // [128], this layer
                 float* __restrict__ h, unsigned short* __restrict__ hb) {
    __shared__ float eps[VBv*HC];                    // 32 KB
    {
        const float4* s4 = (const float4*)eprojf;
        float4* d4 = (float4*)eps;
        int t = threadIdx.x;
        #pragma unroll
        for (int i = 0; i < 4; ++i) d4[t + i*512] = s4[t + i*512];
    }
    __syncthreads();

    int wave = threadIdx.x >> 6;
    int lane = threadIdx.x & 63;
    int n = blockIdx.x*8 + wave;                     // 60000/8 = 7500 exact
    int loff = lane*8;                               // = h*128 + (l&15)*8

    float xrf[8], attf[8];
    {
        bf16x8 xv = *(const bf16x8*)(xlr + (size_t)n*1024 + 512 + loff);
        #pragma unroll
        for (int u = 0; u < 8; ++u) xrf[u] = bf2f((unsigned short)xv[u]);
        float4 a0 = *(const float4*)(att + loff);
        float4 a1 = *(const float4*)(att + loff + 4);
        attf[0]=a0.x; attf[1]=a0.y; attf[2]=a0.z; attf[3]=a0.w;
        attf[4]=a1.x; attf[5]=a1.y; attf[6]=a1.z; attf[7]=a1.w;
    }

    float acc[8] = {0,0,0,0,0,0,0,0};
    float wsum = 0.f;
    int beg = rowptr[n], end = rowptr[n+1];

    int p = beg;
    for (; p + 2 <= end; p += 2) {                   // 2 edges in flight
        int pk0 = packed[p], pk1 = packed[p+1];
        int s0 = pk0 & 0xFFFF, ea0 = pk0 >> 16;
        int s1 = pk1 & 0xFFFF, ea1 = pk1 >> 16;
        bf16x8 v0 = *(const bf16x8*)(xlr + (size_t)s0*1024 + loff);
        bf16x8 v1 = *(const bf16x8*)(xlr + (size_t)s1*1024 + loff);
        const float* ep0 = eps + ea0*HC + loff;
        const float* ep1 = eps + ea1*HC + loff;
        float4 e00 = *(const float4*)ep0, e01 = *(const float4*)(ep0+4);
        float4 e10 = *(const float4*)ep1, e11 = *(const float4*)(ep1+4);
        float xf0[8], xf1[8], epa[8], epb[8];
        epa[0]=e00.x; epa[1]=e00.y; epa[2]=e00.z; epa[3]=e00.w;
        epa[4]=e01.x; epa[5]=e01.y; epa[6]=e01.z; epa[7]=e01.w;
        epb[0]=e10.x; epb[1]=e10.y; epb[2]=e10.z; epb[3]=e10.w;
        epb[4]=e11.x; epb[5]=e11.y; epb[6]=e11.z; epb[7]=e11.w;
        float p0 = 0.f, p1 = 0.f;
        #pragma unroll
        for (int u = 0; u < 8; ++u) {
            xf0[u] = bf2f((unsigned short)v0[u]);
            xf1[u] = bf2f((unsigned short)v1[u]);
            float z0 = xf0[u] + xrf[u] + epa[u];
            float z1 = xf1[u] + xrf[u] + epb[u];
            p0 = fmaf(fmaxf(z0, 0.2f*z0), attf[u], p0);
            p1 = fmaf(fmaxf(z1, 0.2f*z1), attf[u], p1);
        }
        p0 += __shfl_xor(p0, 1); p1 += __shfl_xor(p1, 1);
        p0 += __shfl_xor(p0, 2); p1 += __shfl_xor(p1, 2);
        p0 += __shfl_xor(p0, 4); p1 += __shfl_xor(p1, 4);
        p0 += __shfl_xor(p0, 8); p1 += __shfl_xor(p1, 8);
        float w0 = __expf(p0), w1 = __expf(p1);
        wsum += w0 + w1;
        #pragma unroll
        for (int u = 0; u < 8; ++u) {
            acc[u] = fmaf(w0, xf0[u], acc[u]);
            acc[u] = fmaf(w1, xf1[u], acc[u]);
        }
    }
    if (p < end) {                                   // tail edge
        int pk0 = packed[p];
        int s0 = pk0 & 0xFFFF, ea0 = pk0 >> 16;
        bf16x8 v0 = *(const bf16x8*)(xlr + (size_t)s0*1024 + loff);
        const float* ep0 = eps + ea0*HC + loff;
        float4 e00 = *(const float4*)ep0, e01 = *(const float4*)(ep0+4);
        float epa[8];
        epa[0]=e00.x; epa[1]=e00.y; epa[2]=e00.z; epa[3]=e00.w;
        epa[4]=e01.x; epa[5]=e01.y; epa[6]=e01.z; epa[7]=e01.w;
        float xf0[8];
        float p0 = 0.f;
        #pragma unroll
        for (int u = 0; u < 8; ++u) {
            xf0[u] = bf2f((unsigned short)v0[u]);
            float z0 = xf0[u] + xrf[u] + epa[u];
            p0 = fmaf(fmaxf(z0, 0.2f*z0), attf[u], p0);
        }
        p0 += __shfl_xor(p0, 1);
        p0 += __shfl_xor(p0, 2);
        p0 += __shfl_xor(p0, 4);
        p0 += __shfl_xor(p0, 8);
        float w0 = __expf(p0);
        wsum += w0;
        #pragma unroll
        for (int u = 0; u < 8; ++u) acc[u] = fmaf(w0, xf0[u], acc[u]);
    }

    float inv = __builtin_amdgcn_rcpf(wsum + 1e-16f);
    float rr[8];
    #pragma unroll
    for (int u = 0; u < 8; ++u) rr[u] = acc[u] * inv;
    #pragma unroll
    for (int u = 0; u < 8; ++u) rr[u] += __shfl_xor(rr[u], 16);
    #pragma unroll
    for (int u = 0; u < 8; ++u) rr[u] += __shfl_xor(rr[u], 32);

    if (lane < 16) {
        int c = lane*8;
        float* hp = h + (size_t)n*DD + c;
        float4 h0 = *(const float4*)hp;
        float4 h1 = *(const float4*)(hp + 4);
        float4 b0 = *(const float4*)(bias + c);
        float4 b1 = *(const float4*)(bias + c + 4);
        float o[8];
        o[0] = h0.x + fmaxf(0.f, fmaf(0.25f, rr[0], b0.x));
        o[1] = h0.y + fmaxf(0.f, fmaf(0.25f, rr[1], b0.y));
        o[2] = h0.z + fmaxf(0.f, fmaf(0.25f, rr[2], b0.z));
        o[3] = h0.w + fmaxf(0.f, fmaf(0.25f, rr[3], b0.w));
        o[4] = h1.x + fmaxf(0.f, fmaf(0.25f, rr[4], b1.x));
        o[5] = h1.y + fmaxf(0.f, fmaf(0.25f, rr[5], b1.y));
        o[6] = h1.z + fmaxf(0.f, fmaf(0.25f, rr[6], b1.z));
        o[7] = h1.w + fmaxf(0.f, fmaf(0.25f, rr[7], b1.w));
        *(float4*)hp       = make_float4(o[0], o[1], o[2], o[3]);
        *(float4*)(hp + 4) = make_float4(o[4], o[5], o[6], o[7]);
        ushort4 u0 = make_ushort4(f2bf(o[0]), f2bf(o[1]), f2bf(o[2]), f2bf(o[3]));
        ushort4 u1 = make_ushort4(f2bf(o[4]), f2bf(o[5]), f2bf(o[6]), f2bf(o[7]));
        unsigned short* hbp = hb + (size_t)n*DD + c;
        *(ushort4*)hbp       = u0;
        *(ushort4*)(hbp + 4) = u1;
    }
}

// ---------------- bond head: thread per edge, bf16 gathers, scalar Wb ----------------
__global__ __launch_bounds__(256)
void k_bond(const unsigned short* __restrict__ hb,
            const int* __restrict__ srcv, const int* __restrict__ dstv,
            const float* __restrict__ Wb, const float* __restrict__ bb,
            float* __restrict__ out) {
    int e = blockIdx.x*256 + threadIdx.x;
    if (e >= NE) return;
    int s = srcv[e], d = dstv[e];
    const bf16x8* hs = (const bf16x8*)(hb + (size_t)s*DD);
    const bf16x8* hd = (const bf16x8*)(hb + (size_t)d*DD);
    float acc[16];
    #pragma unroll
    for (int j = 0; j < 16; ++j) acc[j] = bb[j];
    for (int c = 0; c < 16; ++c) {
        bf16x8 v = hs[c];
        #pragma unroll
        for (int u = 0; u < 8; ++u) {
            float a = bf2f((unsigned short)v[u]);
            const float* w = Wb + (size_t)(c*8 + u)*16;
            #pragma unroll
            for (int j = 0; j < 16; ++j) acc[j] = fmaf(a, w[j], acc[j]);
        }
    }
    for (int c = 0; c < 16; ++c) {
        bf16x8 v = hd[c];
        #pragma unroll
        for (int u = 0; u < 8; ++u) {
            float a = bf2f((unsigned short)v[u]);
            const float* w = Wb + (size_t)(128 + c*8 + u)*16;
            #pragma unroll
            for (int j = 0; j < 16; ++j) acc[j] = fmaf(a, w[j], acc[j]);
        }
    }
    float4* o = (float4*)(out + (size_t)e*16);
    o[0] = make_float4(acc[0],  acc[1],  acc[2],  acc[3]);
    o[1] = make_float4(acc[4],  acc[5],  acc[6],  acc[7]);
    o[2] = make_float4(acc[8],  acc[9],  acc[10], acc[11]);
    o[3] = make_float4(acc[12], acc[13], acc[14], acc[15]);
}

// ---------------- host ----------------
extern "C" void kernel_launch(void* const* d_in, const int* in_sizes, int n_in,
                              void* d_out, int out_size, void* d_ws, size_t ws_size,
                              hipStream_t stream) {
    const int*   x        = (const int*)d_in[0];
    const int*   edge_idx = (const int*)d_in[1];
    const int*   eattr    = (const int*)d_in[2];
    const float* atom_emb = (const float*)d_in[3];
    const float* bond_emb = (const float*)d_in[4];
    const float* Wl  = (const float*)d_in[5];
    const float* bl  = (const float*)d_in[6];
    const float* Wr  = (const float*)d_in[7];
    const float* br  = (const float*)d_in[8];
    const float* We  = (const float*)d_in[9];
    const float* att = (const float*)d_in[10];
    const float* bias= (const float*)d_in[11];
    const float* Wa  = (const float*)d_in[12];
    const float* ba  = (const float*)d_in[13];
    const float* Wb  = (const float*)d_in[14];
    const float* bb  = (const float*)d_in[15];

    const int* src = edge_idx;
    const int* dst = edge_idx + NE;

    char* p = (char*)d_ws;
    auto alloc = [&](size_t bytes) -> void* {
        void* r = p; p += (bytes + 255) & ~(size_t)255; return r;
    };
    float*          h      = (float*)alloc((size_t)NN*DD*4);
    unsigned short* hb     = (unsigned short*)alloc((size_t)NN*DD*2);
    unsigned short* xlr    = (unsigned short*)alloc((size_t)NN*1024*2);
    unsigned short* Wlrt   = (unsigned short*)alloc((size_t)NL*1024*DD*2);
    float*          blr    = (float*)alloc((size_t)NL*1024*4);
    unsigned short* Wat    = (unsigned short*)alloc((size_t)DD*VAv*2);
    float*          eprojf = (float*)alloc((size_t)NL*VBv*HC*4);
    int*            deg    = (int*)alloc((size_t)NN*4);
    int*            exc    = (int*)alloc((size_t)NN*4);
    int*            sums   = (int*)alloc(256*4);
    int*            rowptr = (int*)alloc((size_t)(NN+1)*4);
    int*            cnt    = (int*)alloc((size_t)NN*4);
    int*            packed = (int*)alloc((size_t)NE*4);

    float* atom_out = (float*)d_out;                      // [NN,128]
    float* bond_out = atom_out + (size_t)NN*VAv;          // [NE,16]

    hipMemsetAsync(deg, 0, (size_t)NN*4, stream);
    hipMemsetAsync(cnt, 0, (size_t)NN*4, stream);

    k_embed<<<7500, 256, 0, stream>>>(x, atom_emb, h, hb);
    k_convw<<<(NL*1024*DD + 255)/256, 256, 0, stream>>>(Wl, Wr, bl, br, Wlrt, blr);
    k_convwa<<<(DD*VAv + 255)/256, 256, 0, stream>>>(Wa, Wat);
    k_eproj<<<(NL*VBv*HC + 255)/256, 256, 0, stream>>>(bond_emb, We, eprojf);

    // CSR by dst
    int nchunks = (NN + SCAN_CHUNK - 1) / SCAN_CHUNK;     // 118
    k_deg<<<(NE+255)/256, 256, 0, stream>>>(dst, deg);
    k_scan1<<<nchunks, SCAN_CHUNK, 0, stream>>>(deg, exc, sums);
    k_scan2<<<1, 128, 0, stream>>>(sums, nchunks);
    k_scan3<<<(NN+256)/256, 256, 0, stream>>>(exc, sums, rowptr);
    k_scatter<<<(NE+255)/256, 256, 0, stream>>>(src, dst, eattr, rowptr, cnt, packed);

    int mtiles = (NN + 127) / 128;     // 469
    for (int l = 0; l < NL; ++l) {
        const float* att_l  = att  + (size_t)l*NH*VAv;
        const float* bias_l = bias + (size_t)l*DD;
        const unsigned short* Wlrt_l = Wlrt + (size_t)l*1024*DD;
        const float* blr_l = blr + (size_t)l*1024;
        const float* ep_l  = eprojf + (size_t)l*VBv*HC;

        k_gemm_mfma<true><<<dim3(1024/128, mtiles), 256, 0, stream>>>(hb, Wlrt_l, blr_l, xlr, NN, 1024);
        k_aggregate<<<NN/8, 512, 0, stream>>>(xlr, ep_l, rowptr, packed, att_l, bias_l, h, hb);
    }

    k_gemm_mfma<false><<<dim3(VAv/128, mtiles), 256, 0, stream>>>(hb, Wat, ba, atom_out, NN, VAv);
    k_bond<<<(NE+255)/256, 256, 0, stream>>>(hb, src, dst, Wb, bb, bond_out);
}

// Round 6
// 594.567 us; speedup vs baseline: 1.0723x; 1.0723x over previous
//
#include <hip/hip_runtime.h>
#include <hip/hip_bf16.h>
#include <math.h>

#define NN 60000
#define NE 200000
#define DD 128
#define NH 4
#define HC 512   // NH * C
#define NL 3
#define VAv 128
#define VBv 16
#define SCAN_CHUNK 512

typedef __attribute__((ext_vector_type(8))) short bf16x8;
typedef __attribute__((ext_vector_type(4))) float f32x4;

__device__ __forceinline__ float bf2f(unsigned short u){
    union{unsigned int i; float f;} v; v.i = ((unsigned int)u)<<16; return v.f;
}
__device__ __forceinline__ unsigned short f2bf(float f){
    union{float f; unsigned int i;} v; v.f = f;
    unsigned int r = v.i + 0x7fffu + ((v.i>>16)&1u);
    return (unsigned short)(r>>16);
}

#define GLOAD_LDS16(g, l) \
    __builtin_amdgcn_global_load_lds((const __attribute__((address_space(1))) void*)(g), \
                                     (__attribute__((address_space(3))) void*)(l), 16, 0, 0)

// ---------------- embedding gather: h[n,:] = atom_emb[x[n],:] (fp32 + bf16) ----------
__global__ void k_embed(const int* __restrict__ x, const float* __restrict__ atom_emb,
                        float* __restrict__ h, unsigned short* __restrict__ hb) {
    int idx = blockIdx.x*blockDim.x + threadIdx.x;   // float4 index
    if (idx >= NN*(DD/4)) return;
    int n = idx >> 5;
    int c4 = idx & 31;
    int a = x[n];
    float4 v = ((const float4*)(atom_emb + (size_t)a*DD))[c4];
    ((float4*)(h + (size_t)n*DD))[c4] = v;
    ushort4 u = make_ushort4(f2bf(v.x), f2bf(v.y), f2bf(v.z), f2bf(v.w));
    ((ushort4*)(hb + (size_t)n*DD))[c4] = u;
}

// -------- weight convert: [Wl|Wr] -> Wlrt[l][1024][128] bf16 transposed; blr ---------
__global__ void k_convw(const float* __restrict__ Wl, const float* __restrict__ Wr,
                        const float* __restrict__ bl, const float* __restrict__ br,
                        unsigned short* __restrict__ Wlrt, float* __restrict__ blr) {
    int t = blockIdx.x*256 + threadIdx.x;
    if (t < NL*1024*DD) {
        int l = t / (1024*DD);
        int r = t % (1024*DD);
        int n = r / DD;      // 0..1023
        int k = r % DD;
        float v = (n < HC) ? Wl[(size_t)l*DD*HC + (size_t)k*HC + n]
                           : Wr[(size_t)l*DD*HC + (size_t)k*HC + (n - HC)];
        Wlrt[t] = f2bf(v);
    }
    if (t < NL*1024) {
        int l = t / 1024, j = t % 1024;
        blr[t] = (j < HC) ? bl[(size_t)l*HC + j] : br[(size_t)l*HC + (j - HC)];
    }
}

// ---------------- Wa convert: fp32 [128][128] -> bf16 transposed ---------------------
__global__ void k_convwa(const float* __restrict__ Wa, unsigned short* __restrict__ Wat) {
    int t = blockIdx.x*256 + threadIdx.x;
    if (t >= DD*VAv) return;
    int n = t / DD;
    int k = t % DD;
    Wat[t] = f2bf(Wa[(size_t)k*VAv + n]);
}

// ---------------- eproj (all layers, fp32): eprojf[l][v][n] ---------------------------
__global__ void k_eproj(const float* __restrict__ bond_emb, const float* __restrict__ We,
                        float* __restrict__ eprojf) {
    int t = blockIdx.x*256 + threadIdx.x;    // 24576 total
    if (t >= NL*VBv*HC) return;
    int n = t & (HC-1);
    int v = (t >> 9) & (VBv-1);
    int l = t >> 13;
    const float* be = bond_emb + (size_t)v*DD;         // wave-uniform -> scalar
    const float* w  = We + (size_t)l*DD*HC + n;
    float acc = 0.f;
    #pragma unroll 8
    for (int k = 0; k < DD; ++k) acc = fmaf(be[k], w[(size_t)k*HC], acc);
    eprojf[t] = acc;
}

// ---------------- CSR build ----------------
__global__ void k_deg(const int* __restrict__ dst, int* __restrict__ deg) {
    int e = blockIdx.x*blockDim.x + threadIdx.x;
    if (e < NE) atomicAdd(&deg[dst[e]], 1);
}

__global__ void k_scan1(const int* __restrict__ deg, int* __restrict__ exc, int* __restrict__ sums) {
    __shared__ int buf[2][SCAN_CHUNK];
    int t = threadIdx.x;
    int gi = blockIdx.x*SCAN_CHUNK + t;
    int v = (gi < NN) ? deg[gi] : 0;
    buf[0][t] = v;
    __syncthreads();
    int cur = 0;
    for (int off = 1; off < SCAN_CHUNK; off <<= 1) {
        int nv = buf[cur][t] + ((t >= off) ? buf[cur][t-off] : 0);
        buf[cur^1][t] = nv;
        __syncthreads();
        cur ^= 1;
    }
    if (gi < NN) exc[gi] = buf[cur][t] - v;
    if (t == SCAN_CHUNK-1) sums[blockIdx.x] = buf[cur][t];
}

__global__ void k_scan2(int* sums, int nb) {     // nb <= 128
    __shared__ int buf[2][128];
    int t = threadIdx.x;
    int v = (t < nb) ? sums[t] : 0;
    buf[0][t] = v;
    __syncthreads();
    int cur = 0;
    for (int off = 1; off < 128; off <<= 1) {
        int nv = buf[cur][t] + ((t >= off) ? buf[cur][t-off] : 0);
        buf[cur^1][t] = nv;
        __syncthreads();
        cur ^= 1;
    }
    if (t < nb) sums[t] = buf[cur][t] - v;       // exclusive
}

__global__ void k_scan3(const int* __restrict__ exc, const int* __restrict__ sums,
                        int* __restrict__ rowptr) {
    int i = blockIdx.x*blockDim.x + threadIdx.x;
    if (i < NN) rowptr[i] = exc[i] + sums[i / SCAN_CHUNK];
    if (i == NN) rowptr[NN] = NE;
}

// scatter: store src | (eattr<<16) sorted by dst  (src < 65536, eattr < 16)
__global__ void k_scatter(const int* __restrict__ srcv, const int* __restrict__ dst,
                          const int* __restrict__ eattr, const int* __restrict__ rowptr,
                          int* __restrict__ cnt, int* __restrict__ packed) {
    int e = blockIdx.x*blockDim.x + threadIdx.x;
    if (e < NE) {
        int d = dst[e];
        int pos = atomicAdd(&cnt[d], 1);
        packed[rowptr[d] + pos] = srcv[e] | (eattr[e] << 16);
    }
}

// ---------------- MFMA bf16 GEMM v3: pipelined multi-m-tile per block ----------------
// C[M,Nc] = A[M,128] * Bt[Nc,128]^T (+bias). Each block owns one 128-col n-tile and MT
// consecutive 128-row m-tiles. A double-buffered in LDS (2x32 KB, ^(row&15) swizzle,
// conflict-free); B fragments in registers, loaded ONCE and reused for all MT tiles.
// 2-phase pipeline: stage tile t+1 (global_load_lds DMA) while computing tile t.
template<bool OUT_BF16, int MT>
__global__ __launch_bounds__(256)
void k_gemm_mfma(const unsigned short* __restrict__ A,
                 const unsigned short* __restrict__ Bt,
                 const float* __restrict__ bias, void* __restrict__ Cout,
                 int M, int Nc) {
    __shared__ unsigned short As[2][128*128];      // 64 KB
    const int tid = threadIdx.x;
    const int lane = tid & 63;
    const int wave = tid >> 6;
    const int bn = blockIdx.x * 128;
    const int bm0 = blockIdx.y * (128*MT);
    const int l15 = lane & 15;
    const int l4  = lane >> 4;
    const int wm = (wave >> 1) * 64;
    const int wn = (wave & 1) * 64;

    // B fragments once (L2-hot), reused across all MT tiles
    bf16x8 bfr[4][4];
    #pragma unroll
    for (int ks = 0; ks < 4; ++ks)
        #pragma unroll
        for (int ni = 0; ni < 4; ++ni)
            bfr[ks][ni] = *(const bf16x8*)(Bt + (size_t)(bn + wn + ni*16 + l15)*128
                                              + (size_t)(ks*4 + l4)*8);

    // stage A m-tile into LDS buffer `buf` (source-side swizzle: slot c holds chunk c^(row&15))
    auto stage = [&](int buf, int bm) {
        #pragma unroll
        for (int it = 0; it < 8; ++it) {
            int slot = it*256 + tid;        // 16B-chunk slot, 2048 per tile
            int row  = slot >> 4;
            int cph  = slot & 15;
            int clog = cph ^ (row & 15);
            int arow = bm + row; if (arow >= M) arow = M - 1;
            unsigned short* ldst = &As[buf][(size_t)(it*256 + (tid & ~63))*8];
            GLOAD_LDS16(A + (size_t)arow*128 + clog*8, ldst);
        }
    };

    stage(0, bm0);
    asm volatile("s_waitcnt vmcnt(0)" ::: "memory");
    __syncthreads();

    int cur = 0;
    for (int t = 0; t < MT; ++t) {
        int bm = bm0 + t*128;
        if (bm >= M) break;
        if (t+1 < MT && bm + 128 < M) stage(cur^1, bm + 128);   // prefetch next tile

        f32x4 acc[4][4];
        #pragma unroll
        for (int i = 0; i < 4; ++i)
            #pragma unroll
            for (int j = 0; j < 4; ++j)
                acc[i][j] = (f32x4){0.f, 0.f, 0.f, 0.f};

        #pragma unroll
        for (int ks = 0; ks < 4; ++ks) {
            bf16x8 af[4];
            int cph = (ks*4 + l4) ^ l15;           // row&15 == l15 for fragment rows
            #pragma unroll
            for (int mi = 0; mi < 4; ++mi) {
                int row = wm + mi*16 + l15;
                af[mi] = *(const bf16x8*)(&As[cur][(size_t)row*128 + cph*8]);
            }
            #pragma unroll
            for (int mi = 0; mi < 4; ++mi)
                #pragma unroll
                for (int ni = 0; ni < 4; ++ni)
                    acc[mi][ni] = __builtin_amdgcn_mfma_f32_16x16x32_bf16(af[mi], bfr[ks][ni], acc[mi][ni], 0, 0, 0);
        }

        #pragma unroll
        for (int mi = 0; mi < 4; ++mi) {
            #pragma unroll
            for (int ni = 0; ni < 4; ++ni) {
                int col = bn + wn + ni*16 + l15;
                float bv = bias ? bias[col] : 0.f;
                #pragma unroll
                for (int r = 0; r < 4; ++r) {
                    int row = bm + wm + mi*16 + l4*4 + r;
                    if (row < M) {
                        float v = acc[mi][ni][r] + bv;
                        if (OUT_BF16) ((unsigned short*)Cout)[(size_t)row*Nc + col] = f2bf(v);
                        else          ((float*)Cout)[(size_t)row*Nc + col] = v;
                    }
                }
            }
        }

        asm volatile("s_waitcnt vmcnt(0)" ::: "memory");   // next tile's DMA landed
        __syncthreads();
        cur ^= 1;
    }
}

// ---- fused edge-logits + softmax + aggregate + epilogue ----------------------------
// 8 waves/block, one node per wave. Lane l: head h = l>>4, channels (l&15)*8..+8.
// xlr row layout: [xl 512 | xr 512] bf16.
__global__ __launch_bounds__(512)
void k_aggregate(const unsigned short* __restrict__ xlr,
                 const float* __restrict__ eprojf,   // [16][512] fp32, this layer
                 const int* __restrict__ rowptr, const int* __restrict__ packed,
                 const float* __restrict__ att,      // [4][128], this layer
                 const float* __restrict__ bias,     // [128], this layer
                 float* __restrict__ h, unsigned short* __restrict__ hb) {
    __shared__ float eps[VBv*HC];                    // 32 KB
    {
        const float4* s4 = (const float4*)eprojf;
        float4* d4 = (float4*)eps;
        int t = threadIdx.x;
        #pragma unroll
        for (int i = 0; i < 4; ++i) d4[t + i*512] = s4[t + i*512];
    }
    __syncthreads();

    int wave = threadIdx.x >> 6;
    int lane = threadIdx.x & 63;
    int n = blockIdx.x*8 + wave;                     // 60000/8 = 7500 exact
    int loff = lane*8;                               // = h*128 + (l&15)*8

    float xrf[8], attf[8];
    {
        bf16x8 xv = *(const bf16x8*)(xlr + (size_t)n*1024 + 512 + loff);
        #pragma unroll
        for (int u = 0; u < 8; ++u) xrf[u] = bf2f((unsigned short)xv[u]);
        float4 a0 = *(const float4*)(att + loff);
        float4 a1 = *(const float4*)(att + loff + 4);
        attf[0]=a0.x; attf[1]=a0.y; attf[2]=a0.z; attf[3]=a0.w;
        attf[4]=a1.x; attf[5]=a1.y; attf[6]=a1.z; attf[7]=a1.w;
    }

    float acc[8] = {0,0,0,0,0,0,0,0};
    float wsum = 0.f;
    int beg = rowptr[n], end = rowptr[n+1];

    int p = beg;
    for (; p + 2 <= end; p += 2) {                   // 2 edges in flight
        int pk0 = packed[p], pk1 = packed[p+1];
        int s0 = pk0 & 0xFFFF, ea0 = pk0 >> 16;
        int s1 = pk1 & 0xFFFF, ea1 = pk1 >> 16;
        bf16x8 v0 = *(const bf16x8*)(xlr + (size_t)s0*1024 + loff);
        bf16x8 v1 = *(const bf16x8*)(xlr + (size_t)s1*1024 + loff);
        const float* ep0 = eps + ea0*HC + loff;
        const float* ep1 = eps + ea1*HC + loff;
        float4 e00 = *(const float4*)ep0, e01 = *(const float4*)(ep0+4);
        float4 e10 = *(const float4*)ep1, e11 = *(const float4*)(ep1+4);
        float xf0[8], xf1[8], epa[8], epb[8];
        epa[0]=e00.x; epa[1]=e00.y; epa[2]=e00.z; epa[3]=e00.w;
        epa[4]=e01.x; epa[5]=e01.y; epa[6]=e01.z; epa[7]=e01.w;
        epb[0]=e10.x; epb[1]=e10.y; epb[2]=e10.z; epb[3]=e10.w;
        epb[4]=e11.x; epb[5]=e11.y; epb[6]=e11.z; epb[7]=e11.w;
        float p0 = 0.f, p1 = 0.f;
        #pragma unroll
        for (int u = 0; u < 8; ++u) {
            xf0[u] = bf2f((unsigned short)v0[u]);
            xf1[u] = bf2f((unsigned short)v1[u]);
            float z0 = xf0[u] + xrf[u] + epa[u];
            float z1 = xf1[u] + xrf[u] + epb[u];
            p0 = fmaf(fmaxf(z0, 0.2f*z0), attf[u], p0);
            p1 = fmaf(fmaxf(z1, 0.2f*z1), attf[u], p1);
        }
        p0 += __shfl_xor(p0, 1); p1 += __shfl_xor(p1, 1);
        p0 += __shfl_xor(p0, 2); p1 += __shfl_xor(p1, 2);
        p0 += __shfl_xor(p0, 4); p1 += __shfl_xor(p1, 4);
        p0 += __shfl_xor(p0, 8); p1 += __shfl_xor(p1, 8);
        float w0 = __expf(p0), w1 = __expf(p1);
        wsum += w0 + w1;
        #pragma unroll
        for (int u = 0; u < 8; ++u) {
            acc[u] = fmaf(w0, xf0[u], acc[u]);
            acc[u] = fmaf(w1, xf1[u], acc[u]);
        }
    }
    if (p < end) {                                   // tail edge
        int pk0 = packed[p];
        int s0 = pk0 & 0xFFFF, ea0 = pk0 >> 16;
        bf16x8 v0 = *(const bf16x8*)(xlr + (size_t)s0*1024 + loff);
        const float* ep0 = eps + ea0*HC + loff;
        float4 e00 = *(const float4*)ep0, e01 = *(const float4*)(ep0+4);
        float epa[8];
        epa[0]=e00.x; epa[1]=e00.y; epa[2]=e00.z; epa[3]=e00.w;
        epa[4]=e01.x; epa[5]=e01.y; epa[6]=e01.z; epa[7]=e01.w;
        float xf0[8];
        float p0 = 0.f;
        #pragma unroll
        for (int u = 0; u < 8; ++u) {
            xf0[u] = bf2f((unsigned short)v0[u]);
            float z0 = xf0[u] + xrf[u] + epa[u];
            p0 = fmaf(fmaxf(z0, 0.2f*z0), attf[u], p0);
        }
        p0 += __shfl_xor(p0, 1);
        p0 += __shfl_xor(p0, 2);
        p0 += __shfl_xor(p0, 4);
        p0 += __shfl_xor(p0, 8);
        float w0 = __expf(p0);
        wsum += w0;
        #pragma unroll
        for (int u = 0; u < 8; ++u) acc[u] = fmaf(w0, xf0[u], acc[u]);
    }

    float inv = __builtin_amdgcn_rcpf(wsum + 1e-16f);
    float rr[8];
    #pragma unroll
    for (int u = 0; u < 8; ++u) rr[u] = acc[u] * inv;
    #pragma unroll
    for (int u = 0; u < 8; ++u) rr[u] += __shfl_xor(rr[u], 16);
    #pragma unroll
    for (int u = 0; u < 8; ++u) rr[u] += __shfl_xor(rr[u], 32);

    if (lane < 16) {
        int c = lane*8;
        float* hp = h + (size_t)n*DD + c;
        float4 h0 = *(const float4*)hp;
        float4 h1 = *(const float4*)(hp + 4);
        float4 b0 = *(const float4*)(bias + c);
        float4 b1 = *(const float4*)(bias + c + 4);
        float o[8];
        o[0] = h0.x + fmaxf(0.f, fmaf(0.25f, rr[0], b0.x));
        o[1] = h0.y + fmaxf(0.f, fmaf(0.25f, rr[1], b0.y));
        o[2] = h0.z + fmaxf(0.f, fmaf(0.25f, rr[2], b0.z));
        o[3] = h0.w + fmaxf(0.f, fmaf(0.25f, rr[3], b0.w));
        o[4] = h1.x + fmaxf(0.f, fmaf(0.25f, rr[4], b1.x));
        o[5] = h1.y + fmaxf(0.f, fmaf(0.25f, rr[5], b1.y));
        o[6] = h1.z + fmaxf(0.f, fmaf(0.25f, rr[6], b1.z));
        o[7] = h1.w + fmaxf(0.f, fmaf(0.25f, rr[7], b1.w));
        *(float4*)hp       = make_float4(o[0], o[1], o[2], o[3]);
        *(float4*)(hp + 4) = make_float4(o[4], o[5], o[6], o[7]);
        ushort4 u0 = make_ushort4(f2bf(o[0]), f2bf(o[1]), f2bf(o[2]), f2bf(o[3]));
        ushort4 u1 = make_ushort4(f2bf(o[4]), f2bf(o[5]), f2bf(o[6]), f2bf(o[7]));
        unsigned short* hbp = hb + (size_t)n*DD + c;
        *(ushort4*)hbp       = u0;
        *(ushort4*)(hbp + 4) = u1;
    }
}

// ---------------- bond head: thread per edge, bf16 gathers, scalar Wb ----------------
__global__ __launch_bounds__(256)
void k_bond(const unsigned short* __restrict__ hb,
            const int* __restrict__ srcv, const int* __restrict__ dstv,
            const float* __restrict__ Wb, const float* __restrict__ bb,
            float* __restrict__ out) {
    int e = blockIdx.x*256 + threadIdx.x;
    if (e >= NE) return;
    int s = srcv[e], d = dstv[e];
    const bf16x8* hs = (const bf16x8*)(hb + (size_t)s*DD);
    const bf16x8* hd = (const bf16x8*)(hb + (size_t)d*DD);
    float acc[16];
    #pragma unroll
    for (int j = 0; j < 16; ++j) acc[j] = bb[j];
    for (int c = 0; c < 16; ++c) {
        bf16x8 v = hs[c];
        #pragma unroll
        for (int u = 0; u < 8; ++u) {
            float a = bf2f((unsigned short)v[u]);
            const float* w = Wb + (size_t)(c*8 + u)*16;
            #pragma unroll
            for (int j = 0; j < 16; ++j) acc[j] = fmaf(a, w[j], acc[j]);
        }
    }
    for (int c = 0; c < 16; ++c) {
        bf16x8 v = hd[c];
        #pragma unroll
        for (int u = 0; u < 8; ++u) {
            float a = bf2f((unsigned short)v[u]);
            const float* w = Wb + (size_t)(128 + c*8 + u)*16;
            #pragma unroll
            for (int j = 0; j < 16; ++j) acc[j] = fmaf(a, w[j], acc[j]);
        }
    }
    float4* o = (float4*)(out + (size_t)e*16);
    o[0] = make_float4(acc[0],  acc[1],  acc[2],  acc[3]);
    o[1] = make_float4(acc[4],  acc[5],  acc[6],  acc[7]);
    o[2] = make_float4(acc[8],  acc[9],  acc[10], acc[11]);
    o[3] = make_float4(acc[12], acc[13], acc[14], acc[15]);
}

// ---------------- host ----------------
extern "C" void kernel_launch(void* const* d_in, const int* in_sizes, int n_in,
                              void* d_out, int out_size, void* d_ws, size_t ws_size,
                              hipStream_t stream) {
    const int*   x        = (const int*)d_in[0];
    const int*   edge_idx = (const int*)d_in[1];
    const int*   eattr    = (const int*)d_in[2];
    const float* atom_emb = (const float*)d_in[3];
    const float* bond_emb = (const float*)d_in[4];
    const float* Wl  = (const float*)d_in[5];
    const float* bl  = (const float*)d_in[6];
    const float* Wr  = (const float*)d_in[7];
    const float* br  = (const float*)d_in[8];
    const float* We  = (const float*)d_in[9];
    const float* att = (const float*)d_in[10];
    const float* bias= (const float*)d_in[11];
    const float* Wa  = (const float*)d_in[12];
    const float* ba  = (const float*)d_in[13];
    const float* Wb  = (const float*)d_in[14];
    const float* bb  = (const float*)d_in[15];

    const int* src = edge_idx;
    const int* dst = edge_idx + NE;

    char* p = (char*)d_ws;
    auto alloc = [&](size_t bytes) -> void* {
        void* r = p; p += (bytes + 255) & ~(size_t)255; return r;
    };
    float*          h      = (float*)alloc((size_t)NN*DD*4);
    unsigned short* hb     = (unsigned short*)alloc((size_t)NN*DD*2);
    unsigned short* xlr    = (unsigned short*)alloc((size_t)NN*1024*2);
    unsigned short* Wlrt   = (unsigned short*)alloc((size_t)NL*1024*DD*2);
    float*          blr    = (float*)alloc((size_t)NL*1024*4);
    unsigned short* Wat    = (unsigned short*)alloc((size_t)DD*VAv*2);
    float*          eprojf = (float*)alloc((size_t)NL*VBv*HC*4);
    int*            deg    = (int*)alloc((size_t)NN*4);
    int*            exc    = (int*)alloc((size_t)NN*4);
    int*            sums   = (int*)alloc(256*4);
    int*            rowptr = (int*)alloc((size_t)(NN+1)*4);
    int*            cnt    = (int*)alloc((size_t)NN*4);
    int*            packed = (int*)alloc((size_t)NE*4);

    float* atom_out = (float*)d_out;                      // [NN,128]
    float* bond_out = atom_out + (size_t)NN*VAv;          // [NE,16]

    hipMemsetAsync(deg, 0, (size_t)NN*4, stream);
    hipMemsetAsync(cnt, 0, (size_t)NN*4, stream);

    k_embed<<<7500, 256, 0, stream>>>(x, atom_emb, h, hb);
    k_convw<<<(NL*1024*DD + 255)/256, 256, 0, stream>>>(Wl, Wr, bl, br, Wlrt, blr);
    k_convwa<<<(DD*VAv + 255)/256, 256, 0, stream>>>(Wa, Wat);
    k_eproj<<<(NL*VBv*HC + 255)/256, 256, 0, stream>>>(bond_emb, We, eprojf);

    // CSR by dst
    int nchunks = (NN + SCAN_CHUNK - 1) / SCAN_CHUNK;     // 118
    k_deg<<<(NE+255)/256, 256, 0, stream>>>(dst, deg);
    k_scan1<<<nchunks, SCAN_CHUNK, 0, stream>>>(deg, exc, sums);
    k_scan2<<<1, 128, 0, stream>>>(sums, nchunks);
    k_scan3<<<(NN+256)/256, 256, 0, stream>>>(exc, sums, rowptr);
    k_scatter<<<(NE+255)/256, 256, 0, stream>>>(src, dst, eattr, rowptr, cnt, packed);

    const int MTILES = (NN + 127) / 128;                  // 469
    const int GRP8 = (MTILES + 7) / 8;                    // 59
    const int GRP2 = (MTILES + 1) / 2;                    // 235
    for (int l = 0; l < NL; ++l) {
        const float* att_l  = att  + (size_t)l*NH*VAv;
        const float* bias_l = bias + (size_t)l*DD;
        const unsigned short* Wlrt_l = Wlrt + (size_t)l*1024*DD;
        const float* blr_l = blr + (size_t)l*1024;
        const float* ep_l  = eprojf + (size_t)l*VBv*HC;

        k_gemm_mfma<true, 8><<<dim3(1024/128, GRP8), 256, 0, stream>>>(hb, Wlrt_l, blr_l, xlr, NN, 1024);
        k_aggregate<<<NN/8, 512, 0, stream>>>(xlr, ep_l, rowptr, packed, att_l, bias_l, h, hb);
    }

    k_gemm_mfma<false, 2><<<dim3(VAv/128, GRP2), 256, 0, stream>>>(hb, Wat, ba, atom_out, NN, VAv);
    k_bond<<<(NE+255)/256, 256, 0, stream>>>(hb, src, dst, Wb, bb, bond_out);
}

// Round 7
// 469.740 us; speedup vs baseline: 1.3573x; 1.2657x over previous
//
#include <hip/hip_runtime.h>
#include <hip/hip_bf16.h>
#include <math.h>

#define NN 60000
#define NE 200000
#define DD 128
#define NH 4
#define HC 512   // NH * C
#define NL 3
#define VAv 128
#define VBv 16
#define SCAN_CHUNK 512

typedef __attribute__((ext_vector_type(8))) short bf16x8;
typedef __attribute__((ext_vector_type(4))) float f32x4;

__device__ __forceinline__ float bf2f(unsigned short u){
    union{unsigned int i; float f;} v; v.i = ((unsigned int)u)<<16; return v.f;
}
__device__ __forceinline__ unsigned short f2bf(float f){
    union{float f; unsigned int i;} v; v.f = f;
    unsigned int r = v.i + 0x7fffu + ((v.i>>16)&1u);
    return (unsigned short)(r>>16);
}

#define GLOAD_LDS16(g, l) \
    __builtin_amdgcn_global_load_lds((const __attribute__((address_space(1))) void*)(g), \
                                     (__attribute__((address_space(3))) void*)(l), 16, 0, 0)

// ---------------- embedding gather: h[n,:] = atom_emb[x[n],:] (fp32 + bf16) ----------
__global__ void k_embed(const int* __restrict__ x, const float* __restrict__ atom_emb,
                        float* __restrict__ h, unsigned short* __restrict__ hb) {
    int idx = blockIdx.x*blockDim.x + threadIdx.x;   // float4 index
    if (idx >= NN*(DD/4)) return;
    int n = idx >> 5;
    int c4 = idx & 31;
    int a = x[n];
    float4 v = ((const float4*)(atom_emb + (size_t)a*DD))[c4];
    ((float4*)(h + (size_t)n*DD))[c4] = v;
    ushort4 u = make_ushort4(f2bf(v.x), f2bf(v.y), f2bf(v.z), f2bf(v.w));
    ((ushort4*)(hb + (size_t)n*DD))[c4] = u;
}

// -------- weight convert: [Wl|Wr] -> Wlrt[l][1024][128] bf16 transposed; blr ---------
__global__ void k_convw(const float* __restrict__ Wl, const float* __restrict__ Wr,
                        const float* __restrict__ bl, const float* __restrict__ br,
                        unsigned short* __restrict__ Wlrt, float* __restrict__ blr) {
    int t = blockIdx.x*256 + threadIdx.x;
    if (t < NL*1024*DD) {
        int l = t / (1024*DD);
        int r = t % (1024*DD);
        int n = r / DD;      // 0..1023
        int k = r % DD;
        float v = (n < HC) ? Wl[(size_t)l*DD*HC + (size_t)k*HC + n]
                           : Wr[(size_t)l*DD*HC + (size_t)k*HC + (n - HC)];
        Wlrt[t] = f2bf(v);
    }
    if (t < NL*1024) {
        int l = t / 1024, j = t % 1024;
        blr[t] = (j < HC) ? bl[(size_t)l*HC + j] : br[(size_t)l*HC + (j - HC)];
    }
}

// ---------------- Wa convert: fp32 [128][128] -> bf16 transposed ---------------------
__global__ void k_convwa(const float* __restrict__ Wa, unsigned short* __restrict__ Wat) {
    int t = blockIdx.x*256 + threadIdx.x;
    if (t >= DD*VAv) return;
    int n = t / DD;
    int k = t % DD;
    Wat[t] = f2bf(Wa[(size_t)k*VAv + n]);
}

// ---------------- eproj (all layers, fp32): eprojf[l][v][n] ---------------------------
__global__ void k_eproj(const float* __restrict__ bond_emb, const float* __restrict__ We,
                        float* __restrict__ eprojf) {
    int t = blockIdx.x*256 + threadIdx.x;    // 24576 total
    if (t >= NL*VBv*HC) return;
    int n = t & (HC-1);
    int v = (t >> 9) & (VBv-1);
    int l = t >> 13;
    const float* be = bond_emb + (size_t)v*DD;         // wave-uniform -> scalar
    const float* w  = We + (size_t)l*DD*HC + n;
    float acc = 0.f;
    #pragma unroll 8
    for (int k = 0; k < DD; ++k) acc = fmaf(be[k], w[(size_t)k*HC], acc);
    eprojf[t] = acc;
}

// ---------------- CSR build ----------------
__global__ void k_deg(const int* __restrict__ dst, int* __restrict__ deg) {
    int e = blockIdx.x*blockDim.x + threadIdx.x;
    if (e < NE) atomicAdd(&deg[dst[e]], 1);
}

__global__ void k_scan1(const int* __restrict__ deg, int* __restrict__ exc, int* __restrict__ sums) {
    __shared__ int buf[2][SCAN_CHUNK];
    int t = threadIdx.x;
    int gi = blockIdx.x*SCAN_CHUNK + t;
    int v = (gi < NN) ? deg[gi] : 0;
    buf[0][t] = v;
    __syncthreads();
    int cur = 0;
    for (int off = 1; off < SCAN_CHUNK; off <<= 1) {
        int nv = buf[cur][t] + ((t >= off) ? buf[cur][t-off] : 0);
        buf[cur^1][t] = nv;
        __syncthreads();
        cur ^= 1;
    }
    if (gi < NN) exc[gi] = buf[cur][t] - v;
    if (t == SCAN_CHUNK-1) sums[blockIdx.x] = buf[cur][t];
}

__global__ void k_scan2(int* sums, int nb) {     // nb <= 128
    __shared__ int buf[2][128];
    int t = threadIdx.x;
    int v = (t < nb) ? sums[t] : 0;
    buf[0][t] = v;
    __syncthreads();
    int cur = 0;
    for (int off = 1; off < 128; off <<= 1) {
        int nv = buf[cur][t] + ((t >= off) ? buf[cur][t-off] : 0);
        buf[cur^1][t] = nv;
        __syncthreads();
        cur ^= 1;
    }
    if (t < nb) sums[t] = buf[cur][t] - v;       // exclusive
}

__global__ void k_scan3(const int* __restrict__ exc, const int* __restrict__ sums,
                        int* __restrict__ rowptr) {
    int i = blockIdx.x*blockDim.x + threadIdx.x;
    if (i < NN) rowptr[i] = exc[i] + sums[i / SCAN_CHUNK];
    if (i == NN) rowptr[NN] = NE;
}

// scatter: store src | (eattr<<16) sorted by dst  (src < 65536, eattr < 16)
__global__ void k_scatter(const int* __restrict__ srcv, const int* __restrict__ dst,
                          const int* __restrict__ eattr, const int* __restrict__ rowptr,
                          int* __restrict__ cnt, int* __restrict__ packed) {
    int e = blockIdx.x*blockDim.x + threadIdx.x;
    if (e < NE) {
        int d = dst[e];
        int pos = atomicAdd(&cnt[d], 1);
        packed[rowptr[d] + pos] = srcv[e] | (eattr[e] << 16);
    }
}

// ---------------- MFMA bf16 GEMM v4: swapped-operand epilogue + counted vmcnt --------
// C[M,Nc] = A[M,128] * Bt[Nc,128]^T (+bias). mfma(B,A) yields transposed fragments:
// lane holds 4 CONSECUTIVE COLS of one row -> cvt_pk_bf16 + 8B/16B vector stores
// (16 stores/tile/thread vs 64 scalar). Tile boundary: s_waitcnt vmcnt(16) (the 16
// newest = this tile's stores; guarantees the 8 prefetch DMAs done) + raw s_barrier.
template<bool OUT_BF16, int MT>
__global__ __launch_bounds__(256)
void k_gemm_mfma(const unsigned short* __restrict__ A,
                 const unsigned short* __restrict__ Bt,
                 const float* __restrict__ bias, void* __restrict__ Cout,
                 int M, int Nc) {
    __shared__ unsigned short As[2][128*128];      // 64 KB
    const int tid = threadIdx.x;
    const int lane = tid & 63;
    const int wave = tid >> 6;
    const int bn = blockIdx.x * 128;
    const int bm0 = blockIdx.y * (128*MT);
    const int l15 = lane & 15;
    const int l4  = lane >> 4;
    const int wm = (wave >> 1) * 64;
    const int wn = (wave & 1) * 64;

    // B fragments once (L2-hot), reused across all MT tiles
    bf16x8 bfr[4][4];
    #pragma unroll
    for (int ks = 0; ks < 4; ++ks)
        #pragma unroll
        for (int ni = 0; ni < 4; ++ni)
            bfr[ks][ni] = *(const bf16x8*)(Bt + (size_t)(bn + wn + ni*16 + l15)*128
                                              + (size_t)(ks*4 + l4)*8);

    // bias for this thread's 4 cols per ni (cols = bn+wn+ni*16+l4*4 .. +3)
    float4 bv[4];
    #pragma unroll
    for (int ni = 0; ni < 4; ++ni)
        bv[ni] = bias ? *(const float4*)(bias + bn + wn + ni*16 + l4*4)
                      : make_float4(0.f, 0.f, 0.f, 0.f);

    auto stage = [&](int buf, int bm) {
        #pragma unroll
        for (int it = 0; it < 8; ++it) {
            int slot = it*256 + tid;        // 16B-chunk slot, 2048 per tile
            int row  = slot >> 4;
            int cph  = slot & 15;
            int clog = cph ^ (row & 15);
            int arow = bm + row; if (arow >= M) arow = M - 1;
            unsigned short* ldst = &As[buf][(size_t)(it*256 + (tid & ~63))*8];
            GLOAD_LDS16(A + (size_t)arow*128 + clog*8, ldst);
        }
    };

    stage(0, bm0);
    asm volatile("s_waitcnt vmcnt(0)" ::: "memory");
    __syncthreads();

    int cur = 0;
    for (int t = 0; t < MT; ++t) {
        int bm = bm0 + t*128;
        if (bm >= M) break;
        bool pf = (t+1 < MT) && (bm + 128 < M);
        if (pf) stage(cur^1, bm + 128);            // 8 DMA loads in flight

        f32x4 acc[4][4];
        #pragma unroll
        for (int i = 0; i < 4; ++i)
            #pragma unroll
            for (int j = 0; j < 4; ++j)
                acc[i][j] = (f32x4){0.f, 0.f, 0.f, 0.f};

        #pragma unroll
        for (int ks = 0; ks < 4; ++ks) {
            bf16x8 af[4];
            int cph = (ks*4 + l4) ^ l15;           // row&15 == l15 for fragment rows
            #pragma unroll
            for (int mi = 0; mi < 4; ++mi) {
                int row = wm + mi*16 + l15;
                af[mi] = *(const bf16x8*)(&As[cur][(size_t)row*128 + cph*8]);
            }
            #pragma unroll
            for (int mi = 0; mi < 4; ++mi)
                #pragma unroll
                for (int ni = 0; ni < 4; ++ni)
                    // swapped operands: D = (A*B)^T fragment -> lane owns 4 cols of row l15
                    acc[mi][ni] = __builtin_amdgcn_mfma_f32_16x16x32_bf16(bfr[ks][ni], af[mi], acc[mi][ni], 0, 0, 0);
        }

        // epilogue: row = bm+wm+mi*16+l15; cols = bn+wn+ni*16+l4*4 .. +3
        #pragma unroll
        for (int mi = 0; mi < 4; ++mi) {
            int row = bm + wm + mi*16 + l15;
            bool rok = (row < M);
            #pragma unroll
            for (int ni = 0; ni < 4; ++ni) {
                float v0 = acc[mi][ni][0] + bv[ni].x;
                float v1 = acc[mi][ni][1] + bv[ni].y;
                float v2 = acc[mi][ni][2] + bv[ni].z;
                float v3 = acc[mi][ni][3] + bv[ni].w;
                int colb = bn + wn + ni*16 + l4*4;
                if (rok) {
                    if (OUT_BF16) {
                        unsigned int lo, hi;
                        asm("v_cvt_pk_bf16_f32 %0, %1, %2" : "=v"(lo) : "v"(v0), "v"(v1));
                        asm("v_cvt_pk_bf16_f32 %0, %1, %2" : "=v"(hi) : "v"(v2), "v"(v3));
                        *(uint2*)((unsigned short*)Cout + (size_t)row*Nc + colb) = make_uint2(lo, hi);
                    } else {
                        *(float4*)((float*)Cout + (size_t)row*Nc + colb) = make_float4(v0, v1, v2, v3);
                    }
                }
            }
        }

        if (pf) {
            // newest 16 vmem ops are this tile's stores; ensures the 8 DMAs landed
            asm volatile("s_waitcnt vmcnt(16)" ::: "memory");
            __builtin_amdgcn_s_barrier();          // all waves done reading As[cur]
        }
        cur ^= 1;
    }
}

// ---- fused edge-logits + softmax + aggregate + epilogue ----------------------------
// 8 waves/block, one node per wave. Lane l: head h = l>>4, channels (l&15)*8..+8.
// xlr row layout: [xl 512 | xr 512] bf16.
__global__ __launch_bounds__(512)
void k_aggregate(const unsigned short* __restrict__ xlr,
                 const float* __restrict__ eprojf,   // [16][512] fp32, this layer
                 const int* __restrict__ rowptr, const int* __restrict__ packed,
                 const float* __restrict__ att,      // [4][128], this layer
                 const float* __restrict__ bias,     // [128], this layer
                 float* __restrict__ h, unsigned short* __restrict__ hb) {
    __shared__ float eps[VBv*HC];                    // 32 KB
    {
        const float4* s4 = (const float4*)eprojf;
        float4* d4 = (float4*)eps;
        int t = threadIdx.x;
        #pragma unroll
        for (int i = 0; i < 4; ++i) d4[t + i*512] = s4[t + i*512];
    }
    __syncthreads();

    int wave = threadIdx.x >> 6;
    int lane = threadIdx.x & 63;
    int n = blockIdx.x*8 + wave;                     // 60000/8 = 7500 exact
    int loff = lane*8;                               // = h*128 + (l&15)*8

    float xrf[8], attf[8];
    {
        bf16x8 xv = *(const bf16x8*)(xlr + (size_t)n*1024 + 512 + loff);
        #pragma unroll
        for (int u = 0; u < 8; ++u) xrf[u] = bf2f((unsigned short)xv[u]);
        float4 a0 = *(const float4*)(att + loff);
        float4 a1 = *(const float4*)(att + loff + 4);
        attf[0]=a0.x; attf[1]=a0.y; attf[2]=a0.z; attf[3]=a0.w;
        attf[4]=a1.x; attf[5]=a1.y; attf[6]=a1.z; attf[7]=a1.w;
    }

    float acc[8] = {0,0,0,0,0,0,0,0};
    float wsum = 0.f;
    int beg = rowptr[n], end = rowptr[n+1];

    int p = beg;
    for (; p + 2 <= end; p += 2) {                   // 2 edges in flight
        int pk0 = packed[p], pk1 = packed[p+1];
        int s0 = pk0 & 0xFFFF, ea0 = pk0 >> 16;
        int s1 = pk1 & 0xFFFF, ea1 = pk1 >> 16;
        bf16x8 v0 = *(const bf16x8*)(xlr + (size_t)s0*1024 + loff);
        bf16x8 v1 = *(const bf16x8*)(xlr + (size_t)s1*1024 + loff);
        const float* ep0 = eps + ea0*HC + loff;
        const float* ep1 = eps + ea1*HC + loff;
        float4 e00 = *(const float4*)ep0, e01 = *(const float4*)(ep0+4);
        float4 e10 = *(const float4*)ep1, e11 = *(const float4*)(ep1+4);
        float xf0[8], xf1[8], epa[8], epb[8];
        epa[0]=e00.x; epa[1]=e00.y; epa[2]=e00.z; epa[3]=e00.w;
        epa[4]=e01.x; epa[5]=e01.y; epa[6]=e01.z; epa[7]=e01.w;
        epb[0]=e10.x; epb[1]=e10.y; epb[2]=e10.z; epb[3]=e10.w;
        epb[4]=e11.x; epb[5]=e11.y; epb[6]=e11.z; epb[7]=e11.w;
        float p0 = 0.f, p1 = 0.f;
        #pragma unroll
        for (int u = 0; u < 8; ++u) {
            xf0[u] = bf2f((unsigned short)v0[u]);
            xf1[u] = bf2f((unsigned short)v1[u]);
            float z0 = xf0[u] + xrf[u] + epa[u];
            float z1 = xf1[u] + xrf[u] + epb[u];
            p0 = fmaf(fmaxf(z0, 0.2f*z0), attf[u], p0);
            p1 = fmaf(fmaxf(z1, 0.2f*z1), attf[u], p1);
        }
        p0 += __shfl_xor(p0, 1); p1 += __shfl_xor(p1, 1);
        p0 += __shfl_xor(p0, 2); p1 += __shfl_xor(p1, 2);
        p0 += __shfl_xor(p0, 4); p1 += __shfl_xor(p1, 4);
        p0 += __shfl_xor(p0, 8); p1 += __shfl_xor(p1, 8);
        float w0 = __expf(p0), w1 = __expf(p1);
        wsum += w0 + w1;
        #pragma unroll
        for (int u = 0; u < 8; ++u) {
            acc[u] = fmaf(w0, xf0[u], acc[u]);
            acc[u] = fmaf(w1, xf1[u], acc[u]);
        }
    }
    if (p < end) {                                   // tail edge
        int pk0 = packed[p];
        int s0 = pk0 & 0xFFFF, ea0 = pk0 >> 16;
        bf16x8 v0 = *(const bf16x8*)(xlr + (size_t)s0*1024 + loff);
        const float* ep0 = eps + ea0*HC + loff;
        float4 e00 = *(const float4*)ep0, e01 = *(const float4*)(ep0+4);
        float epa[8];
        epa[0]=e00.x; epa[1]=e00.y; epa[2]=e00.z; epa[3]=e00.w;
        epa[4]=e01.x; epa[5]=e01.y; epa[6]=e01.z; epa[7]=e01.w;
        float xf0[8];
        float p0 = 0.f;
        #pragma unroll
        for (int u = 0; u < 8; ++u) {
            xf0[u] = bf2f((unsigned short)v0[u]);
            float z0 = xf0[u] + xrf[u] + epa[u];
            p0 = fmaf(fmaxf(z0, 0.2f*z0), attf[u], p0);
        }
        p0 += __shfl_xor(p0, 1);
        p0 += __shfl_xor(p0, 2);
        p0 += __shfl_xor(p0, 4);
        p0 += __shfl_xor(p0, 8);
        float w0 = __expf(p0);
        wsum += w0;
        #pragma unroll
        for (int u = 0; u < 8; ++u) acc[u] = fmaf(w0, xf0[u], acc[u]);
    }

    float inv = __builtin_amdgcn_rcpf(wsum + 1e-16f);
    float rr[8];
    #pragma unroll
    for (int u = 0; u < 8; ++u) rr[u] = acc[u] * inv;
    #pragma unroll
    for (int u = 0; u < 8; ++u) rr[u] += __shfl_xor(rr[u], 16);
    #pragma unroll
    for (int u = 0; u < 8; ++u) rr[u] += __shfl_xor(rr[u], 32);

    if (lane < 16) {
        int c = lane*8;
        float* hp = h + (size_t)n*DD + c;
        float4 h0 = *(const float4*)hp;
        float4 h1 = *(const float4*)(hp + 4);
        float4 b0 = *(const float4*)(bias + c);
        float4 b1 = *(const float4*)(bias + c + 4);
        float o[8];
        o[0] = h0.x + fmaxf(0.f, fmaf(0.25f, rr[0], b0.x));
        o[1] = h0.y + fmaxf(0.f, fmaf(0.25f, rr[1], b0.y));
        o[2] = h0.z + fmaxf(0.f, fmaf(0.25f, rr[2], b0.z));
        o[3] = h0.w + fmaxf(0.f, fmaf(0.25f, rr[3], b0.w));
        o[4] = h1.x + fmaxf(0.f, fmaf(0.25f, rr[4], b1.x));
        o[5] = h1.y + fmaxf(0.f, fmaf(0.25f, rr[5], b1.y));
        o[6] = h1.z + fmaxf(0.f, fmaf(0.25f, rr[6], b1.z));
        o[7] = h1.w + fmaxf(0.f, fmaf(0.25f, rr[7], b1.w));
        *(float4*)hp       = make_float4(o[0], o[1], o[2], o[3]);
        *(float4*)(hp + 4) = make_float4(o[4], o[5], o[6], o[7]);
        ushort4 u0 = make_ushort4(f2bf(o[0]), f2bf(o[1]), f2bf(o[2]), f2bf(o[3]));
        ushort4 u1 = make_ushort4(f2bf(o[4]), f2bf(o[5]), f2bf(o[6]), f2bf(o[7]));
        unsigned short* hbp = hb + (size_t)n*DD + c;
        *(ushort4*)hbp       = u0;
        *(ushort4*)(hbp + 4) = u1;
    }
}

// ---------------- bond head: thread per edge, bf16 gathers, scalar Wb ----------------
__global__ __launch_bounds__(256)
void k_bond(const unsigned short* __restrict__ hb,
            const int* __restrict__ srcv, const int* __restrict__ dstv,
            const float* __restrict__ Wb, const float* __restrict__ bb,
            float* __restrict__ out) {
    int e = blockIdx.x*256 + threadIdx.x;
    if (e >= NE) return;
    int s = srcv[e], d = dstv[e];
    const bf16x8* hs = (const bf16x8*)(hb + (size_t)s*DD);
    const bf16x8* hd = (const bf16x8*)(hb + (size_t)d*DD);
    float acc[16];
    #pragma unroll
    for (int j = 0; j < 16; ++j) acc[j] = bb[j];
    for (int c = 0; c < 16; ++c) {
        bf16x8 v = hs[c];
        #pragma unroll
        for (int u = 0; u < 8; ++u) {
            float a = bf2f((unsigned short)v[u]);
            const float* w = Wb + (size_t)(c*8 + u)*16;
            #pragma unroll
            for (int j = 0; j < 16; ++j) acc[j] = fmaf(a, w[j], acc[j]);
        }
    }
    for (int c = 0; c < 16; ++c) {
        bf16x8 v = hd[c];
        #pragma unroll
        for (int u = 0; u < 8; ++u) {
            float a = bf2f((unsigned short)v[u]);
            const float* w = Wb + (size_t)(128 + c*8 + u)*16;
            #pragma unroll
            for (int j = 0; j < 16; ++j) acc[j] = fmaf(a, w[j], acc[j]);
        }
    }
    float4* o = (float4*)(out + (size_t)e*16);
    o[0] = make_float4(acc[0],  acc[1],  acc[2],  acc[3]);
    o[1] = make_float4(acc[4],  acc[5],  acc[6],  acc[7]);
    o[2] = make_float4(acc[8],  acc[9],  acc[10], acc[11]);
    o[3] = make_float4(acc[12], acc[13], acc[14], acc[15]);
}

// ---------------- host ----------------
extern "C" void kernel_launch(void* const* d_in, const int* in_sizes, int n_in,
                              void* d_out, int out_size, void* d_ws, size_t ws_size,
                              hipStream_t stream) {
    const int*   x        = (const int*)d_in[0];
    const int*   edge_idx = (const int*)d_in[1];
    const int*   eattr    = (const int*)d_in[2];
    const float* atom_emb = (const float*)d_in[3];
    const float* bond_emb = (const float*)d_in[4];
    const float* Wl  = (const float*)d_in[5];
    const float* bl  = (const float*)d_in[6];
    const float* Wr  = (const float*)d_in[7];
    const float* br  = (const float*)d_in[8];
    const float* We  = (const float*)d_in[9];
    const float* att = (const float*)d_in[10];
    const float* bias= (const float*)d_in[11];
    const float* Wa  = (const float*)d_in[12];
    const float* ba  = (const float*)d_in[13];
    const float* Wb  = (const float*)d_in[14];
    const float* bb  = (const float*)d_in[15];

    const int* src = edge_idx;
    const int* dst = edge_idx + NE;

    char* p = (char*)d_ws;
    auto alloc = [&](size_t bytes) -> void* {
        void* r = p; p += (bytes + 255) & ~(size_t)255; return r;
    };
    float*          h      = (float*)alloc((size_t)NN*DD*4);
    unsigned short* hb     = (unsigned short*)alloc((size_t)NN*DD*2);
    unsigned short* xlr    = (unsigned short*)alloc((size_t)NN*1024*2);
    unsigned short* Wlrt   = (unsigned short*)alloc((size_t)NL*1024*DD*2);
    float*          blr    = (float*)alloc((size_t)NL*1024*4);
    unsigned short* Wat    = (unsigned short*)alloc((size_t)DD*VAv*2);
    float*          eprojf = (float*)alloc((size_t)NL*VBv*HC*4);
    int*            deg    = (int*)alloc((size_t)NN*4);
    int*            exc    = (int*)alloc((size_t)NN*4);
    int*            sums   = (int*)alloc(256*4);
    int*            rowptr = (int*)alloc((size_t)(NN+1)*4);
    int*            cnt    = (int*)alloc((size_t)NN*4);
    int*            packed = (int*)alloc((size_t)NE*4);

    float* atom_out = (float*)d_out;                      // [NN,128]
    float* bond_out = atom_out + (size_t)NN*VAv;          // [NE,16]

    hipMemsetAsync(deg, 0, (size_t)NN*4, stream);
    hipMemsetAsync(cnt, 0, (size_t)NN*4, stream);

    k_embed<<<7500, 256, 0, stream>>>(x, atom_emb, h, hb);
    k_convw<<<(NL*1024*DD + 255)/256, 256, 0, stream>>>(Wl, Wr, bl, br, Wlrt, blr);
    k_convwa<<<(DD*VAv + 255)/256, 256, 0, stream>>>(Wa, Wat);
    k_eproj<<<(NL*VBv*HC + 255)/256, 256, 0, stream>>>(bond_emb, We, eprojf);

    // CSR by dst
    int nchunks = (NN + SCAN_CHUNK - 1) / SCAN_CHUNK;     // 118
    k_deg<<<(NE+255)/256, 256, 0, stream>>>(dst, deg);
    k_scan1<<<nchunks, SCAN_CHUNK, 0, stream>>>(deg, exc, sums);
    k_scan2<<<1, 128, 0, stream>>>(sums, nchunks);
    k_scan3<<<(NN+256)/256, 256, 0, stream>>>(exc, sums, rowptr);
    k_scatter<<<(NE+255)/256, 256, 0, stream>>>(src, dst, eattr, rowptr, cnt, packed);

    const int MTILES = (NN + 127) / 128;                  // 469
    const int GRP4 = (MTILES + 3) / 4;                    // 118
    const int GRP2 = (MTILES + 1) / 2;                    // 235
    for (int l = 0; l < NL; ++l) {
        const float* att_l  = att  + (size_t)l*NH*VAv;
        const float* bias_l = bias + (size_t)l*DD;
        const unsigned short* Wlrt_l = Wlrt + (size_t)l*1024*DD;
        const float* blr_l = blr + (size_t)l*1024;
        const float* ep_l  = eprojf + (size_t)l*VBv*HC;

        k_gemm_mfma<true, 4><<<dim3(1024/128, GRP4), 256, 0, stream>>>(hb, Wlrt_l, blr_l, xlr, NN, 1024);
        k_aggregate<<<NN/8, 512, 0, stream>>>(xlr, ep_l, rowptr, packed, att_l, bias_l, h, hb);
    }

    k_gemm_mfma<false, 2><<<dim3(VAv/128, GRP2), 256, 0, stream>>>(hb, Wat, ba, atom_out, NN, VAv);
    k_bond<<<(NE+255)/256, 256, 0, stream>>>(hb, src, dst, Wb, bb, bond_out);
}